// Round 6
// baseline (1367.208 us; speedup 1.0000x reference)
//
#include <hip/hip_runtime.h>
#include <math.h>

#define B_    2
#define C_    1024
#define N_    80
#define D_    3074
#define DFF_  2048
#define OD_   1026      // C+2
#define QKV_  9222      // 3*D
#define M_    160       // B*N token rows
#define EPS_  1e-5f
#define KPD_  3104      // D_ rounded up to multiple of 32 (bf16 row stride)

typedef __attribute__((ext_vector_type(8))) short bf16x8;   // 8 bf16 = 4 VGPRs
typedef __attribute__((ext_vector_type(4))) float f32x4;

// fp32 -> bf16 (round-to-nearest-even), bit pattern as short
__device__ inline short f2bf(float f) {
    unsigned u = __float_as_uint(f);
    u += 0x7fffu + ((u >> 16) & 1u);
    return (short)(u >> 16);
}

// ---------------------------------------------------------------- reductions
__device__ inline float wave_sum(float v) {
#pragma unroll
    for (int off = 32; off > 0; off >>= 1) v += __shfl_down(v, off, 64);
    return v;
}

__device__ inline float wave_max(float v) {
#pragma unroll
    for (int off = 32; off > 0; off >>= 1) v = fmaxf(v, __shfl_down(v, off, 64));
    return v;
}

__device__ inline void block_reduce_2(float& s, float& s2, float* red) {
    int tid = threadIdx.x;
    int lane = tid & 63, wid = tid >> 6;
    s = wave_sum(s);
    s2 = wave_sum(s2);
    if (lane == 0) { red[wid] = s; red[4 + wid] = s2; }
    __syncthreads();
    if (tid == 0) {
        red[8] = red[0] + red[1] + red[2] + red[3];
        red[9] = red[4] + red[5] + red[6] + red[7];
    }
    __syncthreads();
    s = red[8]; s2 = red[9];
}

// ---------------------------------------------------------------- bilinear
__device__ inline void bilin_setup(int p, int& i0, int& i1, float& t) {
    float s = (p + 0.5f) * 0.0625f - 0.5f;
    s = fminf(fmaxf(s, 0.0f), 13.0f);
    i0 = (int)s;
    t = s - (float)i0;
    i1 = min(i0 + 1, 13);
}

__device__ inline float bilin_tap(const float* f, int y0, int y1, float ty,
                                  int x0, int x1, float tx) {
    float a = f[y0 * 14 + x0], b = f[y0 * 14 + x1];
    float c = f[y1 * 14 + x0], d = f[y1 * 14 + x1];
    return (1.f - ty) * ((1.f - tx) * a + tx * b) + ty * ((1.f - tx) * c + tx * d);
}

// ---------------------------------------------------------------- K0: align
__global__ __launch_bounds__(128) void align_kernel(const int* __restrict__ prev_b,
                                                    const int* __restrict__ first_b,
                                                    int* __restrict__ fb_al) {
    int b = blockIdx.x;
    int tid = threadIdx.x;
    __shared__ int dist[N_];
    __shared__ int bestIdx;
    if (tid < N_) {
        int s = 0;
        for (int j = 0; j < N_; ++j) {
            int src = (j - tid) % N_;
            if (src < 0) src += N_;
            int dy = prev_b[(b * N_ + j) * 2] - first_b[(b * N_ + src) * 2];
            int dx = prev_b[(b * N_ + j) * 2 + 1] - first_b[(b * N_ + src) * 2 + 1];
            s += abs(dy) + abs(dx);
        }
        dist[tid] = s;
    }
    __syncthreads();
    if (tid == 0) {
        int best = 0, bd = dist[0];
        for (int i = 1; i < N_; ++i)
            if (dist[i] < bd) { bd = dist[i]; best = i; }
        bestIdx = best;
    }
    __syncthreads();
    if (tid < N_) {
        int src = (tid - bestIdx) % N_;
        if (src < 0) src += N_;
        fb_al[(b * N_ + tid) * 2]     = first_b[(b * N_ + src) * 2];
        fb_al[(b * N_ + tid) * 2 + 1] = first_b[(b * N_ + src) * 2 + 1];
    }
}

// -------------------------------------------------- K1: pre_q/first_q gather
__global__ __launch_bounds__(256) void gather_init_kernel(
        const float* __restrict__ pre_f, const float* __restrict__ first_f,
        const int* __restrict__ prev_b, const int* __restrict__ fb_al,
        float* __restrict__ pre_q, float* __restrict__ first_q,
        float* __restrict__ curr) {
    int m = blockIdx.x;
    int b = m / N_;
    int tid = threadIdx.x;
    int py = prev_b[m * 2], px = prev_b[m * 2 + 1];
    int fy = fb_al[m * 2], fx = fb_al[m * 2 + 1];
    int py0, py1, px0, px1, fy0, fy1, fx0, fx1;
    float pty, ptx, fty, ftx;
    bilin_setup(py, py0, py1, pty);
    bilin_setup(px, px0, px1, ptx);
    bilin_setup(fy, fy0, fy1, fty);
    bilin_setup(fx, fx0, fx1, ftx);
    for (int c = tid; c < C_; c += 256) {
        const float* fp = pre_f + (size_t)(b * C_ + c) * 196;
        const float* ff = first_f + (size_t)(b * C_ + c) * 196;
        pre_q[(size_t)m * C_ + c]   = bilin_tap(fp, py0, py1, pty, px0, px1, ptx);
        first_q[(size_t)m * C_ + c] = bilin_tap(ff, fy0, fy1, fty, fx0, fx1, ftx);
    }
    if (tid < 2) curr[m * 2 + tid] = (float)prev_b[m * 2 + tid];
}

// -------------------------------------------------- K2: tokens = LN(cat)+pe
__global__ __launch_bounds__(256) void tokens_kernel(
        const float* __restrict__ curr_f, const float* __restrict__ pre_q,
        const float* __restrict__ first_q, const float* __restrict__ curr,
        const float* __restrict__ ln_g, const float* __restrict__ ln_b,
        float* __restrict__ tokens, short* __restrict__ tokens_bf) {
    int m = blockIdx.x;
    int b = m / N_;
    int n = m % N_;
    int tid = threadIdx.x;
    __shared__ float bf[C_];
    __shared__ float red[10];

    float cy = curr[m * 2], cx = curr[m * 2 + 1];
    int iy = (int)cy, ix = (int)cx;
    int y0, y1, x0, x1;
    float ty, tx;
    bilin_setup(iy, y0, y1, ty);
    bilin_setup(ix, x0, x1, tx);
    for (int c = tid; c < C_; c += 256) {
        const float* f = curr_f + (size_t)(b * C_ + c) * 196;
        bf[c] = bilin_tap(f, y0, y1, ty, x0, x1, tx);
    }
    __syncthreads();

    float s = 0.f, s2 = 0.f;
    for (int d = tid; d < D_; d += 256) {
        float v;
        if (d < C_)            v = pre_q[(size_t)m * C_ + d];
        else if (d < 2 * C_)   v = bf[d - C_];
        else if (d == 2 * C_)  v = cy;
        else if (d == 2*C_+1)  v = cx;
        else                   v = first_q[(size_t)m * C_ + (d - 2 * C_ - 2)];
        s += v; s2 += v * v;
    }
    block_reduce_2(s, s2, red);
    float mean = s / (float)D_;
    float var = s2 / (float)D_ - mean * mean;
    float inv = rsqrtf(var + EPS_);

    const float negLogDivD = -logf(10000.0f) / (float)D_;
    for (int d = tid; d < KPD_; d += 256) {
        if (d < D_) {
            float v;
            if (d < C_)            v = pre_q[(size_t)m * C_ + d];
            else if (d < 2 * C_)   v = bf[d - C_];
            else if (d == 2 * C_)  v = cy;
            else if (d == 2*C_+1)  v = cx;
            else                   v = first_q[(size_t)m * C_ + (d - 2 * C_ - 2)];
            float ln = ln_g[d] * (v - mean) * inv + ln_b[d];
            int kk = d >> 1;
            float ang = (float)n * expf((float)(2 * kk) * negLogDivD);
            float pe = (d & 1) ? cosf(ang) : sinf(ang);
            float val = ln + pe;
            tokens[(size_t)m * D_ + d] = val;
            tokens_bf[(size_t)m * KPD_ + d] = f2bf(val);
        } else {
            tokens_bf[(size_t)m * KPD_ + d] = 0;
        }
    }
}

// ---------------------------------------- weight fp32 -> bf16 (zero-padded)
__global__ __launch_bounds__(256) void wcvt_kernel(const float* __restrict__ W,
                                                   short* __restrict__ Wb,
                                                   int K, int KPW) {
    int o = blockIdx.x;
    const float* src = W + (size_t)o * K;
    short* dst = Wb + (size_t)o * KPW;
    for (int k = threadIdx.x; k < KPW; k += 256)
        dst[k] = (k < K) ? f2bf(src[k]) : (short)0;
}

// ------------------------------------------------ bf16-weight MFMA GEMM (SK)
// C[m,o] (+)= sum_{k chunk} A[m,k]*Wb[o,k] via fp32 atomicAdd. Wave owns two
// o-strips sharing A; W register-prefetched 3 chunks deep (the W stream is
// the HBM-latency-bound one); A loaded JIT (L2-resident, 160 rows only).
// Both A and Wb rows are zero-padded to mult-of-32 k -> no ragged tail.
__global__ __launch_bounds__(256) void gemm_bf16_sk(
        const short* __restrict__ A, const short* __restrict__ Wb,
        const float* __restrict__ bias, float* __restrict__ Cout,
        int KPW, int KpA, int O, int KC) {
    int kc0 = blockIdx.y * KC;
    if (kc0 >= KPW) return;
    int nch = (min(KPW, kc0 + KC) - kc0) >> 5;

    int lane = threadIdx.x & 63;
    int wave = threadIdx.x >> 6;
    int col  = lane & 15;
    int quad = lane >> 4;
    int o0 = blockIdx.x * 128 + wave * 32 + col;
    int o1 = o0 + 16;
    int oc0 = min(o0, O - 1), oc1 = min(o1, O - 1);
    const short* w0 = Wb + (size_t)oc0 * KPW + quad * 8 + kc0;
    const short* w1 = Wb + (size_t)oc1 * KPW + quad * 8 + kc0;
    const short* ab = A + (size_t)col * KpA + quad * 8 + kc0;

    f32x4 acc0[10], acc1[10];
#pragma unroll
    for (int t = 0; t < 10; ++t)
#pragma unroll
        for (int r = 0; r < 4; ++r) { acc0[t][r] = 0.f; acc1[t][r] = 0.f; }

    bf16x8 wb0[3], wb1[3];
#pragma unroll
    for (int d = 0; d < 3; ++d)
        if (d < nch) {
            wb0[d] = *(const bf16x8*)(w0 + d * 32);
            wb1[d] = *(const bf16x8*)(w1 + d * 32);
        }
    for (int i = 0; i < nch; ++i) {
        bf16x8 b0 = wb0[0], b1 = wb1[0];
        wb0[0] = wb0[1]; wb0[1] = wb0[2];
        wb1[0] = wb1[1]; wb1[1] = wb1[2];
        if (i + 3 < nch) {
            wb0[2] = *(const bf16x8*)(w0 + (i + 3) * 32);
            wb1[2] = *(const bf16x8*)(w1 + (i + 3) * 32);
        }
        bf16x8 a[10];
#pragma unroll
        for (int t = 0; t < 10; ++t)
            a[t] = *(const bf16x8*)(ab + (size_t)t * 16 * KpA + i * 32);
#pragma unroll
        for (int t = 0; t < 10; ++t) {
            acc0[t] = __builtin_amdgcn_mfma_f32_16x16x32_bf16(a[t], b0, acc0[t], 0, 0, 0);
            acc1[t] = __builtin_amdgcn_mfma_f32_16x16x32_bf16(a[t], b1, acc1[t], 0, 0, 0);
        }
    }
    if (o0 < O) {
        float bv = (blockIdx.y == 0) ? bias[o0] : 0.f;
#pragma unroll
        for (int t = 0; t < 10; ++t)
#pragma unroll
            for (int r = 0; r < 4; ++r)
                atomicAdd(&Cout[(size_t)(t * 16 + quad * 4 + r) * O + o0], acc0[t][r] + bv);
    }
    if (o1 < O) {
        float bv = (blockIdx.y == 0) ? bias[o1] : 0.f;
#pragma unroll
        for (int t = 0; t < 10; ++t)
#pragma unroll
            for (int r = 0; r < 4; ++r)
                atomicAdd(&Cout[(size_t)(t * 16 + quad * 4 + r) * O + o1], acc1[t][r] + bv);
    }
}

// ------------------------------------------------ fp32-weight fallback (SK)
// Used only if ws_size can't hold the bf16 weight mirror.
__global__ __launch_bounds__(256) void gemm_mfma_sk(
        const short* __restrict__ A, const float* __restrict__ Wf,
        const float* __restrict__ bias, float* __restrict__ Cout,
        int K, int KpA, int O, int KC) {
    int kc0 = blockIdx.y * KC;
    if (kc0 >= K) return;
    int kend = min(K, kc0 + KC);

    int lane = threadIdx.x & 63;
    int wave = threadIdx.x >> 6;
    int col  = lane & 15;
    int quad = lane >> 4;
    int o0 = blockIdx.x * 128 + wave * 32 + col;
    int o1 = o0 + 16;
    int oc0 = min(o0, O - 1), oc1 = min(o1, O - 1);

    const float* wrow0 = Wf + (size_t)oc0 * K + quad * 8;
    const float* wrow1 = Wf + (size_t)oc1 * K + quad * 8;
    const short* abase = A + (size_t)col * KpA + quad * 8;

    f32x4 acc0[10], acc1[10];
#pragma unroll
    for (int t = 0; t < 10; ++t)
#pragma unroll
        for (int r = 0; r < 4; ++r) { acc0[t][r] = 0.f; acc1[t][r] = 0.f; }

    int nfull = (kend - kc0) >> 5;
    bf16x8 aCur[10];
    float2 wCur[8];
    if (nfull > 0) {
#pragma unroll
        for (int t = 0; t < 10; ++t)
            aCur[t] = *(const bf16x8*)(abase + (size_t)t * 16 * KpA + kc0);
#pragma unroll
        for (int j = 0; j < 4; ++j) {
            wCur[j]     = *(const float2*)(wrow0 + kc0 + 2 * j);
            wCur[4 + j] = *(const float2*)(wrow1 + kc0 + 2 * j);
        }
    }
    for (int i = 0; i < nfull; ++i) {
        bf16x8 aNxt[10];
        float2 wNxt[8];
        if (i + 1 < nfull) {
            int kn = kc0 + (i + 1) * 32;
#pragma unroll
            for (int t = 0; t < 10; ++t)
                aNxt[t] = *(const bf16x8*)(abase + (size_t)t * 16 * KpA + kn);
#pragma unroll
            for (int j = 0; j < 4; ++j) {
                wNxt[j]     = *(const float2*)(wrow0 + kn + 2 * j);
                wNxt[4 + j] = *(const float2*)(wrow1 + kn + 2 * j);
            }
        }
        bf16x8 b0, b1;
#pragma unroll
        for (int j = 0; j < 4; ++j) {
            b0[2*j] = f2bf(wCur[j].x);     b0[2*j+1] = f2bf(wCur[j].y);
            b1[2*j] = f2bf(wCur[4+j].x);   b1[2*j+1] = f2bf(wCur[4+j].y);
        }
#pragma unroll
        for (int t = 0; t < 10; ++t) {
            acc0[t] = __builtin_amdgcn_mfma_f32_16x16x32_bf16(aCur[t], b0, acc0[t], 0, 0, 0);
            acc1[t] = __builtin_amdgcn_mfma_f32_16x16x32_bf16(aCur[t], b1, acc1[t], 0, 0, 0);
        }
#pragma unroll
        for (int t = 0; t < 10; ++t) aCur[t] = aNxt[t];
#pragma unroll
        for (int j = 0; j < 8; ++j) wCur[j] = wNxt[j];
    }
    int kmain = kc0 + nfull * 32;
    if (kmain < kend) {
        bf16x8 b0, b1;
#pragma unroll
        for (int j = 0; j < 8; ++j) {
            int k = kmain + quad * 8 + j;
            b0[j] = (k < kend) ? f2bf(Wf[(size_t)oc0 * K + k]) : (short)0;
            b1[j] = (k < kend) ? f2bf(Wf[(size_t)oc1 * K + k]) : (short)0;
        }
#pragma unroll
        for (int t = 0; t < 10; ++t) {
            bf16x8 af = *(const bf16x8*)(abase + (size_t)t * 16 * KpA + kmain);
            acc0[t] = __builtin_amdgcn_mfma_f32_16x16x32_bf16(af, b0, acc0[t], 0, 0, 0);
            acc1[t] = __builtin_amdgcn_mfma_f32_16x16x32_bf16(af, b1, acc1[t], 0, 0, 0);
        }
    }
    if (o0 < O) {
        float bv = (blockIdx.y == 0) ? bias[o0] : 0.f;
#pragma unroll
        for (int t = 0; t < 10; ++t)
#pragma unroll
            for (int r = 0; r < 4; ++r)
                atomicAdd(&Cout[(size_t)(t * 16 + quad * 4 + r) * O + o0], acc0[t][r] + bv);
    }
    if (o1 < O) {
        float bv = (blockIdx.y == 0) ? bias[o1] : 0.f;
#pragma unroll
        for (int t = 0; t < 10; ++t)
#pragma unroll
            for (int r = 0; r < 4; ++r)
                atomicAdd(&Cout[(size_t)(t * 16 + quad * 4 + r) * O + o1], acc1[t][r] + bv);
    }
}

// ------------------------------------------------ relu + bf16 convert (ff1)
__global__ __launch_bounds__(256) void relu_cvt_kernel(const float* __restrict__ in,
                                                       short* __restrict__ out,
                                                       int n) {
    int i = blockIdx.x * 256 + threadIdx.x;
    if (i < n) out[i] = f2bf(fmaxf(in[i], 0.f));
}

// ---------------------------------------- qkv fp32 -> padded bf16 q/k/vT
// q_bf,k_bf: [M_][KPD_]; vT: [B_][KPD_][96] (cols 80..95 stay zero)
__global__ __launch_bounds__(256) void qkv_cvt_kernel(const float* __restrict__ qkv,
                                                      short* __restrict__ q_bf,
                                                      short* __restrict__ k_bf,
                                                      short* __restrict__ vT) {
    int m = blockIdx.x;
    int b = m / N_, q = m % N_;
    const float* src = qkv + (size_t)m * QKV_;
    for (int d = threadIdx.x; d < KPD_; d += 256) {
        short qv = (d < D_) ? f2bf(src[d])          : (short)0;
        short kv = (d < D_) ? f2bf(src[D_ + d])     : (short)0;
        short vv = (d < D_) ? f2bf(src[2 * D_ + d]) : (short)0;
        q_bf[(size_t)m * KPD_ + d] = qv;
        k_bf[(size_t)m * KPD_ + d] = kv;
        vT[((size_t)b * KPD_ + d) * 96 + q] = vv;
    }
}

// ------------------------------------------------ scores = Q·K^T via MFMA
__global__ __launch_bounds__(256) void scores_mfma(const short* __restrict__ q_bf,
                                                   const short* __restrict__ k_bf,
                                                   float* __restrict__ sc) {
    int bi = blockIdx.x;
    int b = bi / 25, qt = (bi % 25) / 5, kt = bi % 5;
    int lane = threadIdx.x & 63, wave = threadIdx.x >> 6;
    int col = lane & 15, quad = lane >> 4;
    const short* qbase = q_bf + (size_t)(b * N_ + qt * 16 + col) * KPD_ + quad * 8;
    const short* kbase = k_bf + (size_t)(b * N_ + kt * 16 + col) * KPD_ + quad * 8;
    f32x4 acc;
#pragma unroll
    for (int r = 0; r < 4; ++r) acc[r] = 0.f;
    int c0 = wave * 25, c1 = min(97, c0 + 25);
    for (int c = c0; c < c1; ++c) {
        bf16x8 af = *(const bf16x8*)(qbase + c * 32);
        bf16x8 bf8 = *(const bf16x8*)(kbase + c * 32);
        acc = __builtin_amdgcn_mfma_f32_16x16x32_bf16(af, bf8, acc, 0, 0, 0);
    }
    __shared__ f32x4 red[4][64];
    red[wave][lane] = acc;
    __syncthreads();
    if (threadIdx.x < 64) {
        f32x4 t = red[0][lane];
#pragma unroll
        for (int w = 1; w < 4; ++w)
#pragma unroll
            for (int r = 0; r < 4; ++r) t[r] += red[w][lane][r];
        float scale = rsqrtf((float)D_);
#pragma unroll
        for (int r = 0; r < 4; ++r)
            sc[(size_t)(b * N_ + qt * 16 + quad * 4 + r) * N_ + kt * 16 + col] = t[r] * scale;
    }
}

// ------------------------------------------------ softmax -> p_bf [M_][96]
__global__ __launch_bounds__(256) void softmax_kernel(const float* __restrict__ sc,
                                                      short* __restrict__ p_bf) {
    int m = blockIdx.x * 4 + (threadIdx.x >> 6);
    int lane = threadIdx.x & 63;
    const float* row = sc + (size_t)m * N_;
    float a = row[lane];
    float bv = (lane < 16) ? row[64 + lane] : -1e30f;
    float mx = wave_max(fmaxf(a, bv));
    mx = __shfl(mx, 0, 64);
    float e0 = expf(a - mx);
    float e1 = (lane < 16) ? expf(bv - mx) : 0.f;
    float sum = wave_sum(e0 + e1);
    sum = __shfl(sum, 0, 64);
    float rs = 1.0f / sum;
    p_bf[(size_t)m * 96 + lane] = f2bf(e0 * rs);
    if (lane < 32)
        p_bf[(size_t)m * 96 + 64 + lane] = (lane < 16) ? f2bf(e1 * rs) : (short)0;
}

// ------------------------------------------------ av = P·V via MFMA (vT layout)
__global__ __launch_bounds__(256) void av_mfma(const short* __restrict__ p_bf,
                                               const short* __restrict__ vT,
                                               short* __restrict__ av_bf) {
    int bi = blockIdx.x;
    int b = bi / 49, g = bi % 49;
    int lane = threadIdx.x & 63, wave = threadIdx.x >> 6;
    int dtile = g * 4 + wave;
    if (dtile >= 194) return;          // no barriers below
    int d0 = dtile * 16;
    int col = lane & 15, quad = lane >> 4;
    const short* pbase = p_bf + (size_t)b * N_ * 96 + quad * 8;
    const short* vb = vT + ((size_t)b * KPD_ + d0 + col) * 96 + quad * 8;
    f32x4 acc[5];
#pragma unroll
    for (int t = 0; t < 5; ++t)
#pragma unroll
        for (int r = 0; r < 4; ++r) acc[t][r] = 0.f;
#pragma unroll
    for (int c = 0; c < 3; ++c) {      // K = 96 = 3 chunks of 32
        bf16x8 bf8 = *(const bf16x8*)(vb + c * 32);
#pragma unroll
        for (int t = 0; t < 5; ++t) {
            bf16x8 af = *(const bf16x8*)(pbase + (size_t)(t * 16 + col) * 96 + c * 32);
            acc[t] = __builtin_amdgcn_mfma_f32_16x16x32_bf16(af, bf8, acc[t], 0, 0, 0);
        }
    }
#pragma unroll
    for (int t = 0; t < 5; ++t)
#pragma unroll
        for (int r = 0; r < 4; ++r)
            av_bf[(size_t)(b * N_ + t * 16 + quad * 4 + r) * KPD_ + d0 + col] = f2bf(acc[t][r]);
}

// ---------------------------------------------------------------- layernorm
template <bool WF32>
__global__ __launch_bounds__(256) void ln_kernel(const float* __restrict__ xin,
                                                 const float* __restrict__ res,
                                                 const float* __restrict__ g,
                                                 const float* __restrict__ bta,
                                                 float* __restrict__ outf,
                                                 short* __restrict__ outb) {
    int m = blockIdx.x;
    int tid = threadIdx.x;
    __shared__ float red[10];
    const float* xr = xin + (size_t)m * D_;
    const float* rr = res + (size_t)m * D_;
    float s = 0.f, s2 = 0.f;
    for (int d = tid; d < D_; d += 256) {
        float v = xr[d] + rr[d];
        s += v; s2 += v * v;
    }
    block_reduce_2(s, s2, red);
    float mean = s / (float)D_;
    float var = s2 / (float)D_ - mean * mean;
    float inv = rsqrtf(var + EPS_);
    for (int d = tid; d < KPD_; d += 256) {
        if (d < D_) {
            float v = xr[d] + rr[d];
            float y = g[d] * (v - mean) * inv + bta[d];
            if (WF32) outf[(size_t)m * D_ + d] = y;
            outb[(size_t)m * KPD_ + d] = f2bf(y);
        } else {
            outb[(size_t)m * KPD_ + d] = 0;
        }
    }
}

// ---------------------------------------------------------------- update
__global__ __launch_bounds__(256) void update_kernel(const float* __restrict__ outb,
                                                     float* __restrict__ curr,
                                                     float* __restrict__ pre_q,
                                                     float* __restrict__ results) {
    int m = blockIdx.x;
    int tid = threadIdx.x;
    for (int c = tid; c < C_; c += 256)
        pre_q[(size_t)m * C_ + c] += outb[(size_t)m * OD_ + c];
    if (tid < 2) {
        float nc = curr[m * 2 + tid] + outb[(size_t)m * OD_ + C_ + tid];
        nc = fminf(fmaxf(nc, 0.f), 223.f);
        curr[m * 2 + tid] = nc;
        results[m * 2 + tid] = nc;
    }
}

// ---------------------------------------------------------------- launch
extern "C" void kernel_launch(void* const* d_in, const int* in_sizes, int n_in,
                              void* d_out, int out_size, void* d_ws, size_t ws_size,
                              hipStream_t stream) {
    const float* pre_f   = (const float*)d_in[0];
    const float* curr_f  = (const float*)d_in[1];
    const float* first_f = (const float*)d_in[2];
    const int*   prev_b  = (const int*)d_in[3];
    const int*   first_b = (const int*)d_in[4];
    const float* ln_g    = (const float*)d_in[5];
    const float* ln_b    = (const float*)d_in[6];
    const float* ipw     = (const float*)d_in[7];
    const float* ipb     = (const float*)d_in[8];
    const float* opw     = (const float*)d_in[9];
    const float* opb     = (const float*)d_in[10];
    const float* n1g     = (const float*)d_in[11];
    const float* n1b     = (const float*)d_in[12];
    const float* l1w     = (const float*)d_in[13];
    const float* l1b     = (const float*)d_in[14];
    const float* l2w     = (const float*)d_in[15];
    const float* l2b     = (const float*)d_in[16];
    const float* n2g     = (const float*)d_in[17];
    const float* n2b     = (const float*)d_in[18];
    const float* ow      = (const float*)d_in[19];
    const float* ob      = (const float*)d_in[20];
    float* outp = (float*)d_out;

    float* wf = (float*)d_ws;
    size_t off = 0;
    int*   fb_al   = (int*)(wf + off); off += 320;
    float* curr    = wf + off;         off += 320;
    float* pre_q   = wf + off;         off += (size_t)M_ * C_;
    float* first_q = wf + off;         off += (size_t)M_ * C_;
    float* tokens  = wf + off;         off += (size_t)M_ * D_;
    // ---- contiguous split-K accumulator region (single memset per iter) ----
    float* qkv     = wf + off;         off += (size_t)M_ * QKV_;
    float* aout    = wf + off;         off += (size_t)M_ * D_;
    float* ff1f    = wf + off;         off += (size_t)M_ * DFF_;
    float* ffout   = wf + off;         off += (size_t)M_ * D_;
    float* outb    = wf + off;         off += (size_t)M_ * OD_;
    const size_t ZR_BYTES = (size_t)M_ * (QKV_ + D_ + DFF_ + D_ + OD_) * 4;
    // -----------------------------------------------------------------------
    float* xbuf    = wf + off;         off += (size_t)M_ * D_;
    float* sc      = wf + off;         off += (size_t)M_ * N_;
    short* tokens_bf = (short*)(wf + off); off += (size_t)M_ * KPD_ / 2;
    short* x_bf      = (short*)(wf + off); off += (size_t)M_ * KPD_ / 2;
    short* x2_bf     = (short*)(wf + off); off += (size_t)M_ * KPD_ / 2;
    short* av_bf     = (short*)(wf + off); off += (size_t)M_ * KPD_ / 2;
    short* ff1_bf    = (short*)(wf + off); off += (size_t)M_ * DFF_ / 2;
    short* q_bf      = (short*)(wf + off); off += (size_t)M_ * KPD_ / 2;
    short* k_bf      = (short*)(wf + off); off += (size_t)M_ * KPD_ / 2;
    short* vT        = (short*)(wf + off); off += (size_t)B_ * KPD_ * 96 / 2;
    short* p_bf      = (short*)(wf + off); off += (size_t)M_ * 96 / 2;
    // ---- bf16 weight mirror (used only if ws_size permits) ----
    short* ipw_b = (short*)(wf + off); off += (size_t)QKV_ * KPD_ / 2;
    short* opw_b = (short*)(wf + off); off += (size_t)D_ * KPD_ / 2;
    short* l1w_b = (short*)(wf + off); off += (size_t)DFF_ * KPD_ / 2;
    short* l2w_b = (short*)(wf + off); off += (size_t)D_ * DFF_ / 2;
    short* ow_b  = (short*)(wf + off); off += (size_t)OD_ * KPD_ / 2;
    const bool useBf16W = ws_size >= off * 4 + 1024;   // launch-time constant
    (void)in_sizes; (void)n_in; (void)out_size;

    hipLaunchKernelGGL(align_kernel, dim3(B_), dim3(128), 0, stream,
                       prev_b, first_b, fb_al);
    hipLaunchKernelGGL(gather_init_kernel, dim3(M_), dim3(256), 0, stream,
                       pre_f, first_f, prev_b, fb_al, pre_q, first_q, curr);
    // zero vT once (pad cols 80..95 must stay 0; real cols overwritten each iter)
    hipMemsetAsync(vT, 0, (size_t)B_ * KPD_ * 96 * 2, stream);
    if (useBf16W) {   // one-time fp32->bf16 weight mirror (~320 MB streamed once)
        hipLaunchKernelGGL(wcvt_kernel, dim3(QKV_), dim3(256), 0, stream, ipw, ipw_b, D_, KPD_);
        hipLaunchKernelGGL(wcvt_kernel, dim3(D_),   dim3(256), 0, stream, opw, opw_b, D_, KPD_);
        hipLaunchKernelGGL(wcvt_kernel, dim3(DFF_), dim3(256), 0, stream, l1w, l1w_b, D_, KPD_);
        hipLaunchKernelGGL(wcvt_kernel, dim3(D_),   dim3(256), 0, stream, l2w, l2w_b, DFF_, DFF_);
        hipLaunchKernelGGL(wcvt_kernel, dim3(OD_),  dim3(256), 0, stream, ow,  ow_b,  D_, KPD_);
    }

    for (int it = 0; it < 3; ++it) {
        hipMemsetAsync(qkv, 0, ZR_BYTES, stream);   // all 5 accumulators

        hipLaunchKernelGGL(tokens_kernel, dim3(M_), dim3(256), 0, stream,
                           curr_f, pre_q, first_q, curr, ln_g, ln_b, tokens, tokens_bf);
        if (useBf16W) {
            hipLaunchKernelGGL(gemm_bf16_sk, dim3(73, 13), dim3(256), 0, stream,
                               tokens_bf, ipw_b, ipb, qkv, KPD_, KPD_, QKV_, 256);
        } else {
            hipLaunchKernelGGL(gemm_mfma_sk, dim3(73, 13), dim3(256), 0, stream,
                               tokens_bf, ipw, ipb, qkv, D_, KPD_, QKV_, 256);
        }
        hipLaunchKernelGGL(qkv_cvt_kernel, dim3(M_), dim3(256), 0, stream,
                           qkv, q_bf, k_bf, vT);
        hipLaunchKernelGGL(scores_mfma, dim3(50), dim3(256), 0, stream,
                           q_bf, k_bf, sc);
        hipLaunchKernelGGL(softmax_kernel, dim3(40), dim3(256), 0, stream,
                           sc, p_bf);
        hipLaunchKernelGGL(av_mfma, dim3(98), dim3(256), 0, stream,
                           p_bf, vT, av_bf);
        if (useBf16W) {
            hipLaunchKernelGGL(gemm_bf16_sk, dim3(25, 13), dim3(256), 0, stream,
                               av_bf, opw_b, opb, aout, KPD_, KPD_, D_, 256);
        } else {
            hipLaunchKernelGGL(gemm_mfma_sk, dim3(25, 13), dim3(256), 0, stream,
                               av_bf, opw, opb, aout, D_, KPD_, D_, 256);
        }
        hipLaunchKernelGGL((ln_kernel<true>), dim3(M_), dim3(256), 0, stream,
                           tokens, aout, n1g, n1b, xbuf, x_bf);
        if (useBf16W) {
            hipLaunchKernelGGL(gemm_bf16_sk, dim3(16, 13), dim3(256), 0, stream,
                               x_bf, l1w_b, l1b, ff1f, KPD_, KPD_, DFF_, 256);
        } else {
            hipLaunchKernelGGL(gemm_mfma_sk, dim3(16, 13), dim3(256), 0, stream,
                               x_bf, l1w, l1b, ff1f, D_, KPD_, DFF_, 256);
        }
        hipLaunchKernelGGL(relu_cvt_kernel, dim3((M_ * DFF_ + 255) / 256), dim3(256), 0, stream,
                           ff1f, ff1_bf, M_ * DFF_);
        if (useBf16W) {
            hipLaunchKernelGGL(gemm_bf16_sk, dim3(25, 8), dim3(256), 0, stream,
                               ff1_bf, l2w_b, l2b, ffout, DFF_, DFF_, D_, 256);
        } else {
            hipLaunchKernelGGL(gemm_mfma_sk, dim3(25, 8), dim3(256), 0, stream,
                               ff1_bf, l2w, l2b, ffout, DFF_, DFF_, D_, 256);
        }
        hipLaunchKernelGGL((ln_kernel<false>), dim3(M_), dim3(256), 0, stream,
                           xbuf, ffout, n2g, n2b, (float*)nullptr, x2_bf);
        if (useBf16W) {
            hipLaunchKernelGGL(gemm_bf16_sk, dim3(9, 13), dim3(256), 0, stream,
                               x2_bf, ow_b, ob, outb, KPD_, KPD_, OD_, 256);
        } else {
            hipLaunchKernelGGL(gemm_mfma_sk, dim3(9, 13), dim3(256), 0, stream,
                               x2_bf, ow, ob, outb, D_, KPD_, OD_, 256);
        }
        hipLaunchKernelGGL(update_kernel, dim3(M_), dim3(256), 0, stream,
                           outb, curr, pre_q, outp + (size_t)it * M_ * 2);
    }
}